// Round 10
// baseline (5109.166 us; speedup 1.0000x reference)
//
#include <hip/hip_runtime.h>
#include <hip/hip_bf16.h>
#include <stdint.h>
#include <stddef.h>

// ---------- types ----------
typedef __bf16 bf16x8 __attribute__((ext_vector_type(8)));
typedef float  f32x4  __attribute__((ext_vector_type(4)));

// ---------- helpers ----------
__device__ __forceinline__ float fp8e4m3_to_f32(uint32_t b) {
    uint32_t e = (b >> 3) & 15u, m = b & 7u;
    float mag;
    if (e == 0)
        mag = (float)m * (1.0f / 512.0f);
    else
        mag = __uint_as_float(((e + 120u) << 23) | (m << 20));
    return (b & 0x80u) ? -mag : mag;
}

__device__ __forceinline__ unsigned short f32_to_bf16_bits(float f) {
    uint32_t x = __float_as_uint(f);
    uint32_t r = x + 0x7fffu + ((x >> 16) & 1u);   // RNE
    return (unsigned short)(r >> 16);
}

__device__ __forceinline__ void gload_lds16(const void* g, void* l) {
    __builtin_amdgcn_global_load_lds(
        (const __attribute__((address_space(1))) uint32_t*)g,
        (__attribute__((address_space(3))) uint32_t*)l,
        16, 0, 0);
}

// ---------- dtype detector (3-way), validated round 3 (mode 0 = f32) ----------
__global__ void detect_kernel(const uint32_t* __restrict__ w,
                              uint32_t* __restrict__ flag) {
    __shared__ int sF, sB;
    if (threadIdx.x == 0) { sF = 1; sB = 1; }
    __syncthreads();
    int f32ok = 1, bf16ok = 1;
    #pragma unroll
    for (int i = 0; i < 16; ++i) {
        uint32_t u = w[threadIdx.x * 16 + i];
        if (u & 0x000FFFFFu) f32ok = 0;
        if (u & 0x000F000Fu) bf16ok = 0;
    }
    if (!f32ok)  atomicExch(&sF, 0);
    if (!bf16ok) atomicExch(&sB, 0);
    __syncthreads();
    if (threadIdx.x == 0)
        *flag = sF ? 0u : (sB ? 1u : 2u);
}

// ---------- pre-pass 1: x f32 -> bf16 ----------
__global__ void cvt_x_kernel(const float* __restrict__ x,
                             unsigned short* __restrict__ out, size_t n8) {
    size_t stride = (size_t)gridDim.x * blockDim.x;
    for (size_t i = (size_t)blockIdx.x * blockDim.x + threadIdx.x; i < n8; i += stride) {
        const float4* p = (const float4*)(x + i * 8);
        float4 a = p[0], b = p[1];
        union { uint4 v; unsigned short s[8]; } o;
        o.s[0] = f32_to_bf16_bits(a.x); o.s[1] = f32_to_bf16_bits(a.y);
        o.s[2] = f32_to_bf16_bits(a.z); o.s[3] = f32_to_bf16_bits(a.w);
        o.s[4] = f32_to_bf16_bits(b.x); o.s[5] = f32_to_bf16_bits(b.y);
        o.s[6] = f32_to_bf16_bits(b.z); o.s[7] = f32_to_bf16_bits(b.w);
        *(uint4*)(out + i * 8) = o.v;
    }
}

// ---------- pre-pass 2: weight (any mode) -> canonical bf16 ----------
__global__ void prep_w_kernel(const void* __restrict__ wsrc,
                              const uint32_t* __restrict__ flag,
                              unsigned short* __restrict__ out, size_t n8) {
    const uint32_t mode = *flag;
    size_t stride = (size_t)gridDim.x * blockDim.x;
    for (size_t i = (size_t)blockIdx.x * blockDim.x + threadIdx.x; i < n8; i += stride) {
        union { uint4 v; unsigned short s[8]; } o;
        if (mode == 0) {
            const float4* p = (const float4*)((const float*)wsrc + i * 8);
            float4 a = p[0], b = p[1];
            o.s[0] = f32_to_bf16_bits(a.x); o.s[1] = f32_to_bf16_bits(a.y);
            o.s[2] = f32_to_bf16_bits(a.z); o.s[3] = f32_to_bf16_bits(a.w);
            o.s[4] = f32_to_bf16_bits(b.x); o.s[5] = f32_to_bf16_bits(b.y);
            o.s[6] = f32_to_bf16_bits(b.z); o.s[7] = f32_to_bf16_bits(b.w);
        } else if (mode == 1) {
            o.v = *(const uint4*)((const unsigned short*)wsrc + i * 8);
        } else {
            union { uint2 v; uint8_t b[8]; } u;
            u.v = *(const uint2*)((const uint8_t*)wsrc + i * 8);
            #pragma unroll
            for (int j = 0; j < 8; ++j)
                o.s[j] = f32_to_bf16_bits(fp8e4m3_to_f32(u.b[j]));
        }
        *(uint4*)(out + i * 8) = o.v;
    }
}

// ========== 256x256 GEMM: A global->register, B via LDS (64 KiB) ============
// Round-10 delta vs round-9: A-operand BYPASSES LDS. Refined pipe model:
// LDS served 2304 read + 768 write cyc/K-tile/CU vs MFMA 2483 -> near-sum
// (4982 measured). Now: A frags load global->reg one K-tile ahead (AFa/AFb
// ping-pong, static idx); LDS carries only B (reads 768 + writes 384 cyc).
// A-load coalescing: 16-lane groups read 16x64B contiguous; 4 waves/wm
// share 16 KB via L1/L2. LDS 128->64 KiB => 2 blocks/CU co-resident
// (launch_bounds(512,4)) -> independent barrier groups fill stalls.
// vmcnt ledger (issue order per K-tile: A16 then Bstage4):
//   steady: after stage, wait vmcnt(4) -> A(kt+1) + B(kt+1) both landed.
//   tails:  no stage -> vmcnt(0).
// lgkm(0)+barrier#1 after last B ds_read, before stage (WAR on parity).

#define GBM 256
#define GBN 256
#define GBK 64

#define LOADA_(AF, kt) do {                                                    \
    const unsigned short* _ak = Agl + (size_t)(kt) * 64;                       \
    _Pragma("unroll") for (int m = 0; m < 8; ++m) {                            \
        AF[m][0] = *(const bf16x8*)(_ak + vA[m]);                              \
        AF[m][1] = *(const bf16x8*)(_ak + vA[m] + 32);                         \
    }                                                                          \
} while (0)

#define LDB_(base, qn, Bf) do {                                                \
    _Pragma("unroll") for (int n = 0; n < 2; ++n) {                            \
        Bf[n][0] = *(const bf16x8*)((base) + boff0 + ((qn)*4096 + n*2048));    \
        Bf[n][1] = *(const bf16x8*)((base) + boff1 + ((qn)*4096 + n*2048));    \
    }                                                                          \
} while (0)

#define MFMA_(AF, qm, qn, Bf) do {                                             \
    __builtin_amdgcn_s_setprio(1);                                             \
    _Pragma("unroll") for (int m = 0; m < 4; ++m)                              \
    _Pragma("unroll") for (int n = 0; n < 2; ++n)                              \
    _Pragma("unroll") for (int ks = 0; ks < 2; ++ks)                           \
        acc[(qm)*4+m][(qn)*2+n] = __builtin_amdgcn_mfma_f32_16x16x32_bf16(     \
            AF[(qm)*4+m][ks], Bf[n][ks], acc[(qm)*4+m][(qn)*2+n], 0, 0, 0);    \
    __builtin_amdgcn_s_setprio(0);                                             \
} while (0)

#define STAGEB_(kt2) do {                                                      \
    char* _ld = ldsb + (((kt2) & 1) << 15);                                    \
    const uint8_t* _p = gB + (size_t)(kt2) * 128;                              \
    _Pragma("unroll") for (int j = 0; j < 4; ++j)                              \
        gload_lds16(_p + (size_t)j * 64 * KB2, _ld + (sdst + j*8192));         \
} while (0)

// one K-tile body: PRE = load A(kt+1); STG = stage B(kt+2)
#define KBODY_(kt, AFc, AFn_, PRE, STG) do {                                   \
    const char* _lb = ldsb + (((kt) & 1) << 15);                               \
    if (PRE) LOADA_(AFn_, (kt) + 1);                                           \
    LDB_(_lb, 0, BX);                                                          \
    MFMA_(AFc, 0, 0, BX);                                                      \
    LDB_(_lb, 1, BY);                                                          \
    MFMA_(AFc, 0, 1, BY);                                                      \
    asm volatile("s_waitcnt lgkmcnt(0)" ::: "memory");                         \
    __builtin_amdgcn_s_barrier();        /* #1: B reads of parity done */      \
    if (STG) STAGEB_((kt) + 2);                                                \
    MFMA_(AFc, 1, 0, BX);                /* pure-reg, covers stage issue */    \
    MFMA_(AFc, 1, 1, BY);                                                      \
    if (STG) asm volatile("s_waitcnt vmcnt(4)" ::: "memory");                  \
    else     asm volatile("s_waitcnt vmcnt(0)" ::: "memory");                  \
    __builtin_amdgcn_s_barrier();        /* #2: next parity + A ready */       \
} while (0)

__global__ __launch_bounds__(512, 4)
void gemm256_ag(const unsigned short* __restrict__ A,
                const unsigned short* __restrict__ Bw,
                const float* __restrict__ invp,
                const float* __restrict__ bias,
                float* __restrict__ C, int M, int N, int K) {
    __shared__ unsigned short lds[2][GBN * GBK];   // B only: 64 KiB
    char* ldsb = (char*)&lds[0][0];

    const size_t KB2 = (size_t)K * 2;     // bytes per logical row
    const int KT = K / GBK;

    // bijective XCD swizzle (grid % 8 == 0 guaranteed by dispatch guard)
    const int nwg = gridDim.x;
    const int b   = blockIdx.x;
    const int wg  = (b & 7) * (nwg >> 3) + (b >> 3);
    const int MT  = M / GBM;
    const int tm  = wg % MT;
    const int tn  = wg / MT;

    const int t     = threadIdx.x;
    const int lane  = t & 63;
    const int wid   = t >> 6;       // 0..7
    const int wm    = wid >> 2;     // 0..1
    const int wn    = wid & 3;      // 0..3
    const int laneQ = lane & 15;
    const int laneH = lane >> 4;
    const int xorv  = (laneQ & 7) << 4;     // T2 read swizzle (B)
    const int lrow  = lane >> 3;            // staging row-within-8
    const int lcb   = (lane & 7) ^ lrow;    // inverse-swizzled source block

    // ---- B LDS read offsets (unchanged, validated r6-r9) ----
    const int col0  = (0   + laneH * 16) ^ xorv;
    const int col1  = (64  + laneH * 16) ^ xorv;
    const int boff0 = wn * 8192  + laneQ * 128 + col0;
    const int boff1 = wn * 8192  + laneQ * 128 + col1;
    const int sdst  = wid * 1024 + lane * 16;        // staging dest offset

    // ---- A global fragment element-offsets (per-lane, 32-bit) ----
    const unsigned short* Agl = A + (size_t)tm * GBM * K;
    int vA[8];
    #pragma unroll
    for (int m = 0; m < 8; ++m)
        vA[m] = (wm * 128 + m * 16 + laneQ) * K + laneH * 8;

    // ---- B global staging base pointer ----
    const uint8_t* gB = (const uint8_t*)Bw +
        ((size_t)tn * GBN + wid * 8 + lrow) * KB2 + (size_t)lcb * 16;

    f32x4 acc[8][4] = {};
    bf16x8 AFa[8][2], AFb[8][2], BX[2][2], BY[2][2];

    // ---- prologue: stage B(0),B(1); load A(0) frags ----
    STAGEB_(0);
    STAGEB_(1);
    LOADA_(AFa, 0);
    asm volatile("s_waitcnt vmcnt(0)" ::: "memory");
    __builtin_amdgcn_s_barrier();

    for (int kt = 0; kt < KT; kt += 2) {
        const bool st_e = (kt + 2) < KT;
        KBODY_(kt, AFa, AFb, true, st_e);
        const bool pl_o = (kt + 2) < KT;
        const bool st_o = (kt + 3) < KT;
        KBODY_(kt + 1, AFb, AFa, pl_o, st_o);
    }

    // ---- epilogue: C/D layout col=laneQ, row=laneH*4+reg [m89-verified] ----
    const float inv = *invp;
    float bv[4];
    #pragma unroll
    for (int n = 0; n < 4; ++n)
        bv[n] = bias[tn * GBN + wn * 64 + n * 16 + laneQ];

    #pragma unroll
    for (int m = 0; m < 8; ++m) {
        int rowb = tm * GBM + wm * 128 + m * 16 + laneH * 4;
        #pragma unroll
        for (int j = 0; j < 4; ++j) {
            float* cp = C + (size_t)(rowb + j) * N + tn * GBN + wn * 64;
            #pragma unroll
            for (int n = 0; n < 4; ++n)
                cp[n * 16 + laneQ] = acc[m][n][j] * inv + bv[n];
        }
    }
}

// ---------- fallback (insurance, mode-aware) ----------
__global__ void naive_kernel(const float* __restrict__ x,
                             const void* __restrict__ wsrc,
                             const uint32_t* flag,
                             const float* __restrict__ invp,
                             const float* __restrict__ bias,
                             float* __restrict__ out, int M, int N, int K) {
    const uint32_t mode = flag ? *flag : 0u;
    size_t idx = (size_t)blockIdx.x * blockDim.x + threadIdx.x;
    if (idx >= (size_t)M * N) return;
    int m = (int)(idx / N), n = (int)(idx % N);
    const float* xr = x + (size_t)m * K;
    float s = 0.f;
    if (mode == 0) {
        const float* wr = (const float*)wsrc + (size_t)n * K;
        for (int k = 0; k < K; ++k) s += xr[k] * wr[k];
    } else if (mode == 1) {
        const unsigned short* wr = (const unsigned short*)wsrc + (size_t)n * K;
        for (int k = 0; k < K; ++k)
            s += xr[k] * __uint_as_float(((uint32_t)wr[k]) << 16);
    } else {
        const uint8_t* wr = (const uint8_t*)wsrc + (size_t)n * K;
        for (int k = 0; k < K; ++k) s += xr[k] * fp8e4m3_to_f32(wr[k]);
    }
    out[idx] = s * (*invp) + bias[n];
}

extern "C" void kernel_launch(void* const* d_in, const int* in_sizes, int n_in,
                              void* d_out, int out_size, void* d_ws, size_t ws_size,
                              hipStream_t stream) {
    const float*    x    = (const float*)d_in[0];
    const void*     wsrc = d_in[1];
    const float*    inv  = (const float*)d_in[2];
    const float*    bias = (const float*)d_in[3];
    float*          out  = (float*)d_out;

    const int K = in_sizes[1] / in_sizes[3];   // D_IN  = 4096
    const int N = in_sizes[3];                 // D_OUT = 4096
    const int M = in_sizes[0] / K;             // B*S   = 8192

    const size_t needA = (size_t)M * K * sizeof(unsigned short);
    const size_t needB = (size_t)N * K * sizeof(unsigned short);

    const bool shape_ok = (M % GBM) == 0 && (N % GBN) == 0 && (K % GBK) == 0 &&
                          (K / GBK) >= 4 && ((K / GBK) % 2) == 0 &&
                          (((M / GBM) * (N / GBN)) % 8) == 0;

    if (ws_size < needA + needB + 256 || !shape_ok) {
        size_t total = (size_t)M * N;
        uint32_t* flag = (ws_size >= 256) ? (uint32_t*)d_ws : nullptr;
        if (flag) detect_kernel<<<1, 256, 0, stream>>>((const uint32_t*)wsrc, flag);
        naive_kernel<<<(unsigned)((total + 255) / 256), 256, 0, stream>>>(
            x, wsrc, flag, inv, bias, out, M, N, K);
        return;
    }

    uint32_t*       flag = (uint32_t*)d_ws;
    unsigned short* Abf  = (unsigned short*)((char*)d_ws + 256);
    unsigned short* Wbf  = (unsigned short*)((char*)d_ws + 256 + needA);

    detect_kernel<<<1, 256, 0, stream>>>((const uint32_t*)wsrc, flag);
    cvt_x_kernel<<<2048, 256, 0, stream>>>(x, Abf, (size_t)M * K / 8);
    prep_w_kernel<<<2048, 256, 0, stream>>>(wsrc, flag, Wbf, (size_t)N * K / 8);

    dim3 grid((M / GBM) * (N / GBN));
    gemm256_ag<<<grid, 512, 0, stream>>>(Abf, Wbf, inv, bias, out, M, N, K);
}

// Round 11
// 311.035 us; speedup vs baseline: 16.4264x; 16.4264x over previous
//
#include <hip/hip_runtime.h>
#include <hip/hip_bf16.h>
#include <stdint.h>
#include <stddef.h>

// ---------- types ----------
typedef __bf16 bf16x8 __attribute__((ext_vector_type(8)));
typedef float  f32x4  __attribute__((ext_vector_type(4)));

// ---------- helpers ----------
__device__ __forceinline__ float fp8e4m3_to_f32(uint32_t b) {
    uint32_t e = (b >> 3) & 15u, m = b & 7u;
    float mag;
    if (e == 0)
        mag = (float)m * (1.0f / 512.0f);
    else
        mag = __uint_as_float(((e + 120u) << 23) | (m << 20));
    return (b & 0x80u) ? -mag : mag;
}

__device__ __forceinline__ unsigned short f32_to_bf16_bits(float f) {
    uint32_t x = __float_as_uint(f);
    uint32_t r = x + 0x7fffu + ((x >> 16) & 1u);   // RNE
    return (unsigned short)(r >> 16);
}

__device__ __forceinline__ void gload_lds16(const void* g, void* l) {
    __builtin_amdgcn_global_load_lds(
        (const __attribute__((address_space(1))) uint32_t*)g,
        (__attribute__((address_space(3))) uint32_t*)l,
        16, 0, 0);
}

// ---------- dtype detector (3-way), validated round 3 (mode 0 = f32) ----------
__global__ void detect_kernel(const uint32_t* __restrict__ w,
                              uint32_t* __restrict__ flag) {
    __shared__ int sF, sB;
    if (threadIdx.x == 0) { sF = 1; sB = 1; }
    __syncthreads();
    int f32ok = 1, bf16ok = 1;
    #pragma unroll
    for (int i = 0; i < 16; ++i) {
        uint32_t u = w[threadIdx.x * 16 + i];
        if (u & 0x000FFFFFu) f32ok = 0;
        if (u & 0x000F000Fu) bf16ok = 0;
    }
    if (!f32ok)  atomicExch(&sF, 0);
    if (!bf16ok) atomicExch(&sB, 0);
    __syncthreads();
    if (threadIdx.x == 0)
        *flag = sF ? 0u : (sB ? 1u : 2u);
}

// ---------- pre-pass 1: x f32 -> bf16 ----------
__global__ void cvt_x_kernel(const float* __restrict__ x,
                             unsigned short* __restrict__ out, size_t n8) {
    size_t stride = (size_t)gridDim.x * blockDim.x;
    for (size_t i = (size_t)blockIdx.x * blockDim.x + threadIdx.x; i < n8; i += stride) {
        const float4* p = (const float4*)(x + i * 8);
        float4 a = p[0], b = p[1];
        union { uint4 v; unsigned short s[8]; } o;
        o.s[0] = f32_to_bf16_bits(a.x); o.s[1] = f32_to_bf16_bits(a.y);
        o.s[2] = f32_to_bf16_bits(a.z); o.s[3] = f32_to_bf16_bits(a.w);
        o.s[4] = f32_to_bf16_bits(b.x); o.s[5] = f32_to_bf16_bits(b.y);
        o.s[6] = f32_to_bf16_bits(b.z); o.s[7] = f32_to_bf16_bits(b.w);
        *(uint4*)(out + i * 8) = o.v;
    }
}

// ---------- pre-pass 2: weight (any mode) -> canonical bf16 ----------
__global__ void prep_w_kernel(const void* __restrict__ wsrc,
                              const uint32_t* __restrict__ flag,
                              unsigned short* __restrict__ out, size_t n8) {
    const uint32_t mode = *flag;
    size_t stride = (size_t)gridDim.x * blockDim.x;
    for (size_t i = (size_t)blockIdx.x * blockDim.x + threadIdx.x; i < n8; i += stride) {
        union { uint4 v; unsigned short s[8]; } o;
        if (mode == 0) {
            const float4* p = (const float4*)((const float*)wsrc + i * 8);
            float4 a = p[0], b = p[1];
            o.s[0] = f32_to_bf16_bits(a.x); o.s[1] = f32_to_bf16_bits(a.y);
            o.s[2] = f32_to_bf16_bits(a.z); o.s[3] = f32_to_bf16_bits(a.w);
            o.s[4] = f32_to_bf16_bits(b.x); o.s[5] = f32_to_bf16_bits(b.y);
            o.s[6] = f32_to_bf16_bits(b.z); o.s[7] = f32_to_bf16_bits(b.w);
        } else if (mode == 1) {
            o.v = *(const uint4*)((const unsigned short*)wsrc + i * 8);
        } else {
            union { uint2 v; uint8_t b[8]; } u;
            u.v = *(const uint2*)((const uint8_t*)wsrc + i * 8);
            #pragma unroll
            for (int j = 0; j < 8; ++j)
                o.s[j] = f32_to_bf16_bits(fp8e4m3_to_f32(u.b[j]));
        }
        *(uint4*)(out + i * 8) = o.v;
    }
}

// ===== 256x256 GEMM, 16x16x32 MFMA, full-iteration vmcnt slack ==============
// Round-11 delta vs round-8 (r10 reverted: VGPR-cap spill disaster):
// the K-loop is reorganized so the stage->wait distance is a FULL
// iteration (~2500 cyc) instead of ~1 MFMA window (~300-600 cyc) < HBM
// latency (~600-900 cyc). r4-r9 all stalled at the vmcnt every iter.
//   per iter kt:
//     [LDB0,LDA0,MFMA(00),LDB1,MFMA(01),LDA1,MFMA(10),MFMA(11)]  mega-window
//     lgkm0 + barrier      // free: reads consumed by MFMAs; closes WAR
//     stage B(kt+2); stage A(kt+2)    // issue-and-go into parity kt%2
//     vmcnt(more?8:0) + barrier       // kt+1 (issued LAST iter) landed
// Ledger: steady outstanding at vmcnt = (kt+1)'s 8 + (kt+2)'s 8 -> vmcnt(8)
// drains (kt+1) exactly. Tail iters issue no stages -> vmcnt(0) (fixes the
// KT-2 edge where vmcnt(8) would not drain (KT-1)'s loads).

#define GBM 256
#define GBN 256
#define GBK 64

#define LDA_(qm) do {                                                          \
    _Pragma("unroll") for (int m = 0; m < 4; ++m) {                            \
        AF[m][0] = *(const bf16x8*)(ldsA + aoff0 + ((qm)*8192 + m*2048));      \
        AF[m][1] = *(const bf16x8*)(ldsA + aoff1 + ((qm)*8192 + m*2048));      \
    }                                                                          \
} while (0)

#define LDB_(qn, Bf) do {                                                      \
    _Pragma("unroll") for (int n = 0; n < 2; ++n) {                            \
        Bf[n][0] = *(const bf16x8*)(ldsB + boff0 + ((qn)*4096 + n*2048));      \
        Bf[n][1] = *(const bf16x8*)(ldsB + boff1 + ((qn)*4096 + n*2048));      \
    }                                                                          \
} while (0)

#define MFMA_(qm, qn, Bf) do {                                                 \
    __builtin_amdgcn_s_setprio(1);                                             \
    _Pragma("unroll") for (int m = 0; m < 4; ++m)                              \
    _Pragma("unroll") for (int n = 0; n < 2; ++n)                              \
    _Pragma("unroll") for (int ks = 0; ks < 2; ++ks)                           \
        acc[(qm)*4+m][(qn)*2+n] = __builtin_amdgcn_mfma_f32_16x16x32_bf16(     \
            AF[m][ks], Bf[n][ks], acc[(qm)*4+m][(qn)*2+n], 0, 0, 0);           \
    __builtin_amdgcn_s_setprio(0);                                             \
} while (0)

#define STAGE_(gsrc, koff, ldst) do {                                          \
    const uint8_t* _p = (gsrc) + (koff);                                       \
    _Pragma("unroll") for (int j = 0; j < 4; ++j)                              \
        gload_lds16(_p + (size_t)j * 64 * KB2, (ldst) + (sdst + j*8192));      \
} while (0)

__global__ __launch_bounds__(512, 2)
void gemm256_sl(const unsigned short* __restrict__ A,
                const unsigned short* __restrict__ Bw,
                const float* __restrict__ invp,
                const float* __restrict__ bias,
                float* __restrict__ C, int M, int N, int K) {
    __shared__ unsigned short lds[2][2][GBM * GBK];   // 128 KiB
    char* ldsb = (char*)&lds[0][0][0];

    const size_t KB2 = (size_t)K * 2;     // bytes per logical row
    const int KT = K / GBK;

    // bijective XCD swizzle (grid % 8 == 0 guaranteed by dispatch guard)
    const int nwg = gridDim.x;
    const int b   = blockIdx.x;
    const int wg  = (b & 7) * (nwg >> 3) + (b >> 3);
    const int MT  = M / GBM;
    const int tm  = wg % MT;
    const int tn  = wg / MT;

    const int t     = threadIdx.x;
    const int lane  = t & 63;
    const int wid   = t >> 6;       // 0..7
    const int wm    = wid >> 2;     // 0..1
    const int wn    = wid & 3;      // 0..3
    const int laneQ = lane & 15;
    const int laneH = lane >> 4;
    const int xorv  = (laneQ & 7) << 4;     // T2 read swizzle
    const int lrow  = lane >> 3;            // staging row-within-8
    const int lcb   = (lane & 7) ^ lrow;    // inverse-swizzled source block

    // ---- precomputed 32-bit LDS read offsets (validated r6-r9) ----
    const int col0  = (0   + laneH * 16) ^ xorv;
    const int col1  = (64  + laneH * 16) ^ xorv;
    const int aoff0 = wm * 16384 + laneQ * 128 + col0;
    const int aoff1 = wm * 16384 + laneQ * 128 + col1;
    const int boff0 = wn * 8192  + laneQ * 128 + col0;
    const int boff1 = wn * 8192  + laneQ * 128 + col1;
    const int sdst  = wid * 1024 + lane * 16;        // staging dest offset

    // ---- global staging base pointers ----
    const uint8_t* gA = (const uint8_t*)A +
        ((size_t)tm * GBM + wid * 8 + lrow) * KB2 + (size_t)lcb * 16;
    const uint8_t* gB = (const uint8_t*)Bw +
        ((size_t)tn * GBN + wid * 8 + lrow) * KB2 + (size_t)lcb * 16;

    f32x4 acc[8][4] = {};
    bf16x8 AF[4][2], B0[2][2], B1[2][2];

    // ---- prologue: stage tiles 0 (parity 0) and 1 (parity 1) ----
    STAGE_(gB, (size_t)0,   ldsb + 32768);
    STAGE_(gA, (size_t)0,   ldsb);
    STAGE_(gB, (size_t)128, ldsb + 65536 + 32768);
    STAGE_(gA, (size_t)128, ldsb + 65536);
    asm volatile("s_waitcnt vmcnt(8)" ::: "memory");   // tile 0 landed
    __builtin_amdgcn_s_barrier();

    for (int kt = 0; kt < KT; ++kt) {
        const int coff = (kt & 1) << 16;          // 0 / 65536
        const char* ldsA = ldsb + coff;
        const char* ldsB = ldsb + coff + 32768;
        char* ldsAw = (char*)ldsA;                // kt+2 shares parity with kt
        char* ldsBw = (char*)ldsB;
        const bool more = (kt + 2) < KT;
        const size_t kb2 = (size_t)(kt + 2) * 128;

        // ===== mega-window: all 24 reads + all 64 MFMA (no mid barriers) ====
        LDB_(0, B0);
        LDA_(0);
        MFMA_(0, 0, B0);
        LDB_(1, B1);
        MFMA_(0, 1, B1);
        LDA_(1);
        MFMA_(1, 0, B0);
        MFMA_(1, 1, B1);

        asm volatile("s_waitcnt lgkmcnt(0)" ::: "memory");  // free: consumed
        __builtin_amdgcn_s_barrier();   // all waves' kt reads done (WAR gate)

        // ===== stage kt+2 into now-dead parity-kt regions, issue-and-go =====
        if (more) {
            STAGE_(gB, kb2, ldsBw);
            STAGE_(gA, kb2, ldsAw);
        }
        // kt+1's stages were issued a FULL iteration ago -> no latency stall
        if (more) asm volatile("s_waitcnt vmcnt(8)" ::: "memory");
        else      asm volatile("s_waitcnt vmcnt(0)" ::: "memory");
        __builtin_amdgcn_s_barrier();   // kt+1 ready for next iter
    }

    // ---- epilogue: C/D layout col=laneQ, row=laneH*4+reg [m89-verified] ----
    const float inv = *invp;
    float bv[4];
    #pragma unroll
    for (int n = 0; n < 4; ++n)
        bv[n] = bias[tn * GBN + wn * 64 + n * 16 + laneQ];

    #pragma unroll
    for (int m = 0; m < 8; ++m) {
        int rowb = tm * GBM + wm * 128 + m * 16 + laneH * 4;
        #pragma unroll
        for (int j = 0; j < 4; ++j) {
            float* cp = C + (size_t)(rowb + j) * N + tn * GBN + wn * 64;
            #pragma unroll
            for (int n = 0; n < 4; ++n)
                cp[n * 16 + laneQ] = acc[m][n][j] * inv + bv[n];
        }
    }
}

// ---------- fallback (insurance, mode-aware) ----------
__global__ void naive_kernel(const float* __restrict__ x,
                             const void* __restrict__ wsrc,
                             const uint32_t* flag,
                             const float* __restrict__ invp,
                             const float* __restrict__ bias,
                             float* __restrict__ out, int M, int N, int K) {
    const uint32_t mode = flag ? *flag : 0u;
    size_t idx = (size_t)blockIdx.x * blockDim.x + threadIdx.x;
    if (idx >= (size_t)M * N) return;
    int m = (int)(idx / N), n = (int)(idx % N);
    const float* xr = x + (size_t)m * K;
    float s = 0.f;
    if (mode == 0) {
        const float* wr = (const float*)wsrc + (size_t)n * K;
        for (int k = 0; k < K; ++k) s += xr[k] * wr[k];
    } else if (mode == 1) {
        const unsigned short* wr = (const unsigned short*)wsrc + (size_t)n * K;
        for (int k = 0; k < K; ++k)
            s += xr[k] * __uint_as_float(((uint32_t)wr[k]) << 16);
    } else {
        const uint8_t* wr = (const uint8_t*)wsrc + (size_t)n * K;
        for (int k = 0; k < K; ++k) s += xr[k] * fp8e4m3_to_f32(wr[k]);
    }
    out[idx] = s * (*invp) + bias[n];
}

extern "C" void kernel_launch(void* const* d_in, const int* in_sizes, int n_in,
                              void* d_out, int out_size, void* d_ws, size_t ws_size,
                              hipStream_t stream) {
    const float*    x    = (const float*)d_in[0];
    const void*     wsrc = d_in[1];
    const float*    inv  = (const float*)d_in[2];
    const float*    bias = (const float*)d_in[3];
    float*          out  = (float*)d_out;

    const int K = in_sizes[1] / in_sizes[3];   // D_IN  = 4096
    const int N = in_sizes[3];                 // D_OUT = 4096
    const int M = in_sizes[0] / K;             // B*S   = 8192

    const size_t needA = (size_t)M * K * sizeof(unsigned short);
    const size_t needB = (size_t)N * K * sizeof(unsigned short);

    const bool shape_ok = (M % GBM) == 0 && (N % GBN) == 0 && (K % GBK) == 0 &&
                          (K / GBK) >= 2 &&
                          (((M / GBM) * (N / GBN)) % 8) == 0;

    if (ws_size < needA + needB + 256 || !shape_ok) {
        size_t total = (size_t)M * N;
        uint32_t* flag = (ws_size >= 256) ? (uint32_t*)d_ws : nullptr;
        if (flag) detect_kernel<<<1, 256, 0, stream>>>((const uint32_t*)wsrc, flag);
        naive_kernel<<<(unsigned)((total + 255) / 256), 256, 0, stream>>>(
            x, wsrc, flag, inv, bias, out, M, N, K);
        return;
    }

    uint32_t*       flag = (uint32_t*)d_ws;
    unsigned short* Abf  = (unsigned short*)((char*)d_ws + 256);
    unsigned short* Wbf  = (unsigned short*)((char*)d_ws + 256 + needA);

    detect_kernel<<<1, 256, 0, stream>>>((const uint32_t*)wsrc, flag);
    cvt_x_kernel<<<2048, 256, 0, stream>>>(x, Abf, (size_t)M * K / 8);
    prep_w_kernel<<<2048, 256, 0, stream>>>(wsrc, flag, Wbf, (size_t)N * K / 8);

    dim3 grid((M / GBM) * (N / GBN));
    gemm256_sl<<<grid, 512, 0, stream>>>(Abf, Wbf, inv, bias, out, M, N, K);
}

// Round 12
// 298.064 us; speedup vs baseline: 17.1412x; 1.0435x over previous
//
#include <hip/hip_runtime.h>
#include <hip/hip_bf16.h>
#include <stdint.h>
#include <stddef.h>

// ---------- types ----------
typedef __bf16 bf16x8 __attribute__((ext_vector_type(8)));
typedef float  f32x4  __attribute__((ext_vector_type(4)));

// ---------- helpers ----------
__device__ __forceinline__ float fp8e4m3_to_f32(uint32_t b) {
    uint32_t e = (b >> 3) & 15u, m = b & 7u;
    float mag;
    if (e == 0)
        mag = (float)m * (1.0f / 512.0f);
    else
        mag = __uint_as_float(((e + 120u) << 23) | (m << 20));
    return (b & 0x80u) ? -mag : mag;
}

__device__ __forceinline__ unsigned short f32_to_bf16_bits(float f) {
    uint32_t x = __float_as_uint(f);
    uint32_t r = x + 0x7fffu + ((x >> 16) & 1u);   // RNE
    return (unsigned short)(r >> 16);
}

__device__ __forceinline__ void gload_lds16(const void* g, void* l) {
    __builtin_amdgcn_global_load_lds(
        (const __attribute__((address_space(1))) uint32_t*)g,
        (__attribute__((address_space(3))) uint32_t*)l,
        16, 0, 0);
}

// ---------- dtype detector (3-way), validated round 3 (mode 0 = f32) ----------
__global__ void detect_kernel(const uint32_t* __restrict__ w,
                              uint32_t* __restrict__ flag) {
    __shared__ int sF, sB;
    if (threadIdx.x == 0) { sF = 1; sB = 1; }
    __syncthreads();
    int f32ok = 1, bf16ok = 1;
    #pragma unroll
    for (int i = 0; i < 16; ++i) {
        uint32_t u = w[threadIdx.x * 16 + i];
        if (u & 0x000FFFFFu) f32ok = 0;
        if (u & 0x000F000Fu) bf16ok = 0;
    }
    if (!f32ok)  atomicExch(&sF, 0);
    if (!bf16ok) atomicExch(&sB, 0);
    __syncthreads();
    if (threadIdx.x == 0)
        *flag = sF ? 0u : (sB ? 1u : 2u);
}

// ---------- pre-pass 1: x f32 -> bf16 ----------
__global__ void cvt_x_kernel(const float* __restrict__ x,
                             unsigned short* __restrict__ out, size_t n8) {
    size_t stride = (size_t)gridDim.x * blockDim.x;
    for (size_t i = (size_t)blockIdx.x * blockDim.x + threadIdx.x; i < n8; i += stride) {
        const float4* p = (const float4*)(x + i * 8);
        float4 a = p[0], b = p[1];
        union { uint4 v; unsigned short s[8]; } o;
        o.s[0] = f32_to_bf16_bits(a.x); o.s[1] = f32_to_bf16_bits(a.y);
        o.s[2] = f32_to_bf16_bits(a.z); o.s[3] = f32_to_bf16_bits(a.w);
        o.s[4] = f32_to_bf16_bits(b.x); o.s[5] = f32_to_bf16_bits(b.y);
        o.s[6] = f32_to_bf16_bits(b.z); o.s[7] = f32_to_bf16_bits(b.w);
        *(uint4*)(out + i * 8) = o.v;
    }
}

// ---------- pre-pass 2: weight (any mode) -> canonical bf16 ----------
__global__ void prep_w_kernel(const void* __restrict__ wsrc,
                              const uint32_t* __restrict__ flag,
                              unsigned short* __restrict__ out, size_t n8) {
    const uint32_t mode = *flag;
    size_t stride = (size_t)gridDim.x * blockDim.x;
    for (size_t i = (size_t)blockIdx.x * blockDim.x + threadIdx.x; i < n8; i += stride) {
        union { uint4 v; unsigned short s[8]; } o;
        if (mode == 0) {
            const float4* p = (const float4*)((const float*)wsrc + i * 8);
            float4 a = p[0], b = p[1];
            o.s[0] = f32_to_bf16_bits(a.x); o.s[1] = f32_to_bf16_bits(a.y);
            o.s[2] = f32_to_bf16_bits(a.z); o.s[3] = f32_to_bf16_bits(a.w);
            o.s[4] = f32_to_bf16_bits(b.x); o.s[5] = f32_to_bf16_bits(b.y);
            o.s[6] = f32_to_bf16_bits(b.z); o.s[7] = f32_to_bf16_bits(b.w);
        } else if (mode == 1) {
            o.v = *(const uint4*)((const unsigned short*)wsrc + i * 8);
        } else {
            union { uint2 v; uint8_t b[8]; } u;
            u.v = *(const uint2*)((const uint8_t*)wsrc + i * 8);
            #pragma unroll
            for (int j = 0; j < 8; ++j)
                o.s[j] = f32_to_bf16_bits(fp8e4m3_to_f32(u.b[j]));
        }
        *(uint4*)(out + i * 8) = o.v;
    }
}

// ===== 256x256 GEMM, 16x16x32 MFMA, faithful 8-phase fine interleave ========
// Round-12 delta vs round-8/11: the m196/m201 lever — EVERY phase carries
// {ds_read subtile || 1 half-tile stage (2 gloads) || 16 MFMA} with two
// barriers, uniform drumbeat. Liveness-derived stage spread:
//   per K-tile j (buffer p=j&1):
//   P1: LDB(qn0)+LDA(qm0); stage A-half0(j+1)->p^1 [A(p^1) dead since
//       (j-1)P3-close]; lgkm(8); bar; lgkm0; MFMA(0,0); bar
//   P2: LDB(qn1); stage A-half1(j+1); bar; lgkm0; MFMA(0,1); bar
//   P3: LDA(qm1); stage B-half0(j+2)->p [B(p) dead since jP2-close];
//       bar; lgkm0; MFMA(1,1); bar
//   P4: stage B-half1(j+2); bar; MFMA(1,0); vmcnt(4|0); bar
// vmcnt ledger: at jP4, outstanding = B(j) 4? no — = B(j+1)[(j-1)P3P4 left
// over] + A(j+1)[P1P2] + B(j+2)[P3P4] = 12 -> vmcnt(4) drains B(j+1)?? —
// careful: drains 8 OLDEST = B(j+1 is newest...) order: B(j+1) issued
// (j-1)P3P4 (oldest), A(j+1) P1P2, B(j+2) P3P4 (newest). Drain to 4:
// B(j+1)+A(j+1) landed, B(j+2) in flight -> (j+1)'s reads safe. Prologue
// B(0),A(0),B(1) + vmcnt(4) enters the same steady state. Tails vmcnt(0).

#define GBM 256
#define GBN 256
#define GBK 64

#define LDA_(qm) do {                                                          \
    _Pragma("unroll") for (int m = 0; m < 4; ++m) {                            \
        AF[m][0] = *(const bf16x8*)(ldsA + aoff0 + ((qm)*8192 + m*2048));      \
        AF[m][1] = *(const bf16x8*)(ldsA + aoff1 + ((qm)*8192 + m*2048));      \
    }                                                                          \
} while (0)

#define LDB_(qn, Bf) do {                                                      \
    _Pragma("unroll") for (int n = 0; n < 2; ++n) {                            \
        Bf[n][0] = *(const bf16x8*)(ldsB + boff0 + ((qn)*4096 + n*2048));      \
        Bf[n][1] = *(const bf16x8*)(ldsB + boff1 + ((qn)*4096 + n*2048));      \
    }                                                                          \
} while (0)

#define MFMA_(qm, qn, Bf) do {                                                 \
    __builtin_amdgcn_s_setprio(1);                                             \
    _Pragma("unroll") for (int m = 0; m < 4; ++m)                              \
    _Pragma("unroll") for (int n = 0; n < 2; ++n)                              \
    _Pragma("unroll") for (int ks = 0; ks < 2; ++ks)                           \
        acc[(qm)*4+m][(qn)*2+n] = __builtin_amdgcn_mfma_f32_16x16x32_bf16(     \
            AF[m][ks], Bf[n][ks], acc[(qm)*4+m][(qn)*2+n], 0, 0, 0);           \
    __builtin_amdgcn_s_setprio(0);                                             \
} while (0)

// full 256x64 tile (prologue): 4 gloads
#define STAGE_(gsrc, koff, ldst) do {                                          \
    const uint8_t* _p = (gsrc) + (koff);                                       \
    _Pragma("unroll") for (int j = 0; j < 4; ++j)                              \
        gload_lds16(_p + (size_t)j * 64 * KB2, (ldst) + (sdst + j*8192));      \
} while (0)

// half-tile h (rows h*128..h*128+127): 2 gloads
#define STAGEH_(gsrc, koff, ldst, h) do {                                      \
    const uint8_t* _p = (gsrc) + (koff);                                       \
    _Pragma("unroll") for (int j = 2*(h); j < 2*(h) + 2; ++j)                  \
        gload_lds16(_p + (size_t)j * 64 * KB2, (ldst) + (sdst + j*8192));      \
} while (0)

#define BAR_()   __builtin_amdgcn_s_barrier()
#define LGKM0_() asm volatile("s_waitcnt lgkmcnt(0)" ::: "memory")

__global__ __launch_bounds__(512, 2)
void gemm256_p8(const unsigned short* __restrict__ A,
                const unsigned short* __restrict__ Bw,
                const float* __restrict__ invp,
                const float* __restrict__ bias,
                float* __restrict__ C, int M, int N, int K) {
    __shared__ unsigned short lds[2][2][GBM * GBK];   // 128 KiB
    char* ldsb = (char*)&lds[0][0][0];

    const size_t KB2 = (size_t)K * 2;     // bytes per logical row
    const int KT = K / GBK;

    // bijective XCD swizzle (grid % 8 == 0 guaranteed by dispatch guard)
    const int nwg = gridDim.x;
    const int b   = blockIdx.x;
    const int wg  = (b & 7) * (nwg >> 3) + (b >> 3);
    const int MT  = M / GBM;
    const int tm  = wg % MT;
    const int tn  = wg / MT;

    const int t     = threadIdx.x;
    const int lane  = t & 63;
    const int wid   = t >> 6;       // 0..7
    const int wm    = wid >> 2;     // 0..1
    const int wn    = wid & 3;      // 0..3
    const int laneQ = lane & 15;
    const int laneH = lane >> 4;
    const int xorv  = (laneQ & 7) << 4;     // T2 read swizzle
    const int lrow  = lane >> 3;            // staging row-within-8
    const int lcb   = (lane & 7) ^ lrow;    // inverse-swizzled source block

    // ---- precomputed 32-bit LDS read offsets (validated r6-r11) ----
    const int col0  = (0   + laneH * 16) ^ xorv;
    const int col1  = (64  + laneH * 16) ^ xorv;
    const int aoff0 = wm * 16384 + laneQ * 128 + col0;
    const int aoff1 = wm * 16384 + laneQ * 128 + col1;
    const int boff0 = wn * 8192  + laneQ * 128 + col0;
    const int boff1 = wn * 8192  + laneQ * 128 + col1;
    const int sdst  = wid * 1024 + lane * 16;        // staging dest offset

    // ---- global staging base pointers ----
    const uint8_t* gA = (const uint8_t*)A +
        ((size_t)tm * GBM + wid * 8 + lrow) * KB2 + (size_t)lcb * 16;
    const uint8_t* gB = (const uint8_t*)Bw +
        ((size_t)tn * GBN + wid * 8 + lrow) * KB2 + (size_t)lcb * 16;

    f32x4 acc[8][4] = {};
    bf16x8 AF[4][2], B0[2][2], B1[2][2];

    // ---- prologue: B(0), A(0) full; B(1) full; steady-state entry ----
    STAGE_(gB, (size_t)0,   ldsb + 32768);
    STAGE_(gA, (size_t)0,   ldsb);
    STAGE_(gB, (size_t)128, ldsb + 65536 + 32768);
    asm volatile("s_waitcnt vmcnt(4)" ::: "memory");   // tile 0 landed
    BAR_();

    for (int j = 0; j < KT; ++j) {
        const int p = (j & 1) << 16;
        const char* ldsA = ldsb + p;
        const char* ldsB = ldsb + p + 32768;
        char* stA = ldsb + ((~j & 1) << 16);          // A(j+1) -> buffer p^1
        char* stB = ldsb + p + 32768;                 // B(j+2) -> buffer p
        const bool pA = (j + 1) < KT;
        const bool pB = (j + 2) < KT;
        const size_t kA = (size_t)(j + 1) * 128;
        const size_t kB = (size_t)(j + 2) * 128;

        // ---- P1: 12 reads; stage A-half0(j+1); MFMA (0,0) ----
        LDB_(0, B0);
        LDA_(0);
        if (pA) STAGEH_(gA, kA, stA, 0);
        asm volatile("s_waitcnt lgkmcnt(8)" ::: "memory");
        BAR_();  LGKM0_();
        MFMA_(0, 0, B0);
        BAR_();

        // ---- P2: 4 reads; stage A-half1(j+1); MFMA (0,1) ----
        LDB_(1, B1);
        if (pA) STAGEH_(gA, kA, stA, 1);
        BAR_();  LGKM0_();
        MFMA_(0, 1, B1);
        BAR_();

        // ---- P3: 8 reads; stage B-half0(j+2); MFMA (1,1) ----
        LDA_(1);
        if (pB) STAGEH_(gB, kB, stB, 0);
        BAR_();  LGKM0_();
        MFMA_(1, 1, B1);
        BAR_();

        // ---- P4: stage B-half1(j+2); MFMA (1,0); counted vmcnt ----
        if (pB) STAGEH_(gB, kB, stB, 1);
        BAR_();
        MFMA_(1, 0, B0);
        if (pB) asm volatile("s_waitcnt vmcnt(4)" ::: "memory");
        else    asm volatile("s_waitcnt vmcnt(0)" ::: "memory");
        BAR_();
    }

    // ---- epilogue: C/D layout col=laneQ, row=laneH*4+reg [m89-verified] ----
    const float inv = *invp;
    float bv[4];
    #pragma unroll
    for (int n = 0; n < 4; ++n)
        bv[n] = bias[tn * GBN + wn * 64 + n * 16 + laneQ];

    #pragma unroll
    for (int m = 0; m < 8; ++m) {
        int rowb = tm * GBM + wm * 128 + m * 16 + laneH * 4;
        #pragma unroll
        for (int j = 0; j < 4; ++j) {
            float* cp = C + (size_t)(rowb + j) * N + tn * GBN + wn * 64;
            #pragma unroll
            for (int n = 0; n < 4; ++n)
                cp[n * 16 + laneQ] = acc[m][n][j] * inv + bv[n];
        }
    }
}

// ---------- fallback (insurance, mode-aware) ----------
__global__ void naive_kernel(const float* __restrict__ x,
                             const void* __restrict__ wsrc,
                             const uint32_t* flag,
                             const float* __restrict__ invp,
                             const float* __restrict__ bias,
                             float* __restrict__ out, int M, int N, int K) {
    const uint32_t mode = flag ? *flag : 0u;
    size_t idx = (size_t)blockIdx.x * blockDim.x + threadIdx.x;
    if (idx >= (size_t)M * N) return;
    int m = (int)(idx / N), n = (int)(idx % N);
    const float* xr = x + (size_t)m * K;
    float s = 0.f;
    if (mode == 0) {
        const float* wr = (const float*)wsrc + (size_t)n * K;
        for (int k = 0; k < K; ++k) s += xr[k] * wr[k];
    } else if (mode == 1) {
        const unsigned short* wr = (const unsigned short*)wsrc + (size_t)n * K;
        for (int k = 0; k < K; ++k)
            s += xr[k] * __uint_as_float(((uint32_t)wr[k]) << 16);
    } else {
        const uint8_t* wr = (const uint8_t*)wsrc + (size_t)n * K;
        for (int k = 0; k < K; ++k) s += xr[k] * fp8e4m3_to_f32(wr[k]);
    }
    out[idx] = s * (*invp) + bias[n];
}

extern "C" void kernel_launch(void* const* d_in, const int* in_sizes, int n_in,
                              void* d_out, int out_size, void* d_ws, size_t ws_size,
                              hipStream_t stream) {
    const float*    x    = (const float*)d_in[0];
    const void*     wsrc = d_in[1];
    const float*    inv  = (const float*)d_in[2];
    const float*    bias = (const float*)d_in[3];
    float*          out  = (float*)d_out;

    const int K = in_sizes[1] / in_sizes[3];   // D_IN  = 4096
    const int N = in_sizes[3];                 // D_OUT = 4096
    const int M = in_sizes[0] / K;             // B*S   = 8192

    const size_t needA = (size_t)M * K * sizeof(unsigned short);
    const size_t needB = (size_t)N * K * sizeof(unsigned short);

    const bool shape_ok = (M % GBM) == 0 && (N % GBN) == 0 && (K % GBK) == 0 &&
                          (K / GBK) >= 2 &&
                          (((M / GBM) * (N / GBN)) % 8) == 0;

    if (ws_size < needA + needB + 256 || !shape_ok) {
        size_t total = (size_t)M * N;
        uint32_t* flag = (ws_size >= 256) ? (uint32_t*)d_ws : nullptr;
        if (flag) detect_kernel<<<1, 256, 0, stream>>>((const uint32_t*)wsrc, flag);
        naive_kernel<<<(unsigned)((total + 255) / 256), 256, 0, stream>>>(
            x, wsrc, flag, inv, bias, out, M, N, K);
        return;
    }

    uint32_t*       flag = (uint32_t*)d_ws;
    unsigned short* Abf  = (unsigned short*)((char*)d_ws + 256);
    unsigned short* Wbf  = (unsigned short*)((char*)d_ws + 256 + needA);

    detect_kernel<<<1, 256, 0, stream>>>((const uint32_t*)wsrc, flag);
    cvt_x_kernel<<<2048, 256, 0, stream>>>(x, Abf, (size_t)M * K / 8);
    prep_w_kernel<<<2048, 256, 0, stream>>>(wsrc, flag, Wbf, (size_t)N * K / 8);

    dim3 grid((M / GBM) * (N / GBN));
    gemm256_p8<<<grid, 512, 0, stream>>>(Abf, Wbf, inv, bias, out, M, N, K);
}